// Round 8
// baseline (182.549 us; speedup 1.0000x reference)
//
#include <hip/hip_runtime.h>
#include <stdint.h>

#define TH 8
#define W_ 1024
#define H_ 1024

typedef __attribute__((address_space(3))) uint32_t lds_u32;
typedef __attribute__((address_space(1))) const uint32_t glb_u32;

// async global->LDS DMA, 16B/lane; LDS dest = wave-uniform base + lane*16
__device__ __forceinline__ void dma16(const float* g, float* l) {
    __builtin_amdgcn_global_load_lds((glb_u32*)(uintptr_t)g,
                                     (lds_u32*)(uintptr_t)l, 16, 0, 0);
}

#define FENCE() asm volatile("" ::: "memory")

__device__ __forceinline__ float wexp1(float zp, float iz, float kd, float kspat) {
    const float u = fmaf(zp, iz, -1.0f);
    return __builtin_amdgcn_exp2f(fmaf(u * kd, u, kspat));
}

// 5-tap depth-guided blur of (b,d) around center; taps m2,m1,[c],p1,p2
__device__ __forceinline__ void blur5(
    float zm2, float zm1, float zc, float zp1, float zp2,
    float bm2, float bm1, float bc, float bp1, float bp2,
    float dm2, float dm1, float dc, float dp1, float dp2,
    float kd, float ks1, float ks4,
    float& ob, float& od)
{
    const float iz = __builtin_amdgcn_rcpf(zc);
    const float w0 = wexp1(zm2, iz, kd, ks4);
    const float w1 = wexp1(zm1, iz, kd, ks1);
    const float w3 = wexp1(zp1, iz, kd, ks1);
    const float w4 = wexp1(zp2, iz, kd, ks4);
    const float wr = __builtin_amdgcn_rcpf(1.0f + w0 + w1 + w3 + w4);
    ob = fmaf(w0, bm2, fmaf(w1, bm1, fmaf(w3, bp1, fmaf(w4, bp2, bc)))) * wr;
    od = fmaf(w0, dm2, fmaf(w1, dm1, fmaf(w3, dp1, fmaf(w4, dp2, dc)))) * wr;
}

__device__ __forceinline__ float blend1(float bc, float dc, float bm, float dm,
                                        float de, float dke, float ce) {
    const float devb = __builtin_amdgcn_exp2f(
        de * __builtin_amdgcn_logf(fmaxf(fabsf(bc - bm), 1e-8f))) * ce;
    const float devd = fmaxf(__builtin_amdgcn_exp2f(
        de * __builtin_amdgcn_logf(fmaxf(fabsf(dc - dm), 1e-8f))), dke);
    const float wr = __builtin_amdgcn_rcpf(devb + devd);
    return fmaf(devd, bc, devb * dc) * wr;
}

// wave-uniform halo taps (2 cols left of span, 2 right) for z,b,d.
// Only lanes 0 and 63 consume these; all lanes hold them (uniform loads).
struct Halo { float2 lz, rz, lb, rb, ld, rd; };

// 6 register loads, clamped addresses (uniform counts for the vmcnt ledger;
// garbage at image edges is neutralized: z poisoned at use, b/d get weight 0)
__device__ __forceinline__ void halo_load(
    int gy, const float* __restrict__ bB, const float* __restrict__ dB,
    const float* __restrict__ zB, int hl, int hr, Halo& h)
{
    const int gyc = min(max(gy, 0), H_ - 1);
    const size_t ro = (size_t)gyc * W_;
    h.lz = *(const float2*)(zB + ro + hl);
    h.rz = *(const float2*)(zB + ro + hr);
    h.lb = *(const float2*)(bB + ro + hl);
    h.rb = *(const float2*)(bB + ro + hr);
    h.ld = *(const float2*)(dB + ro + hl);
    h.rd = *(const float2*)(dB + ro + hr);
}

// 3 async DMAs for row gy into a slot (wave-private 256-float span at wb)
__device__ __forceinline__ void dma_row(
    int gy, const float* __restrict__ bB, const float* __restrict__ dB,
    const float* __restrict__ zB,
    float* sZs, float* sBs, float* sDs, int c, int wb)
{
    const int gyc = min(max(gy, 0), H_ - 1);
    const size_t ro = (size_t)gyc * W_;
    dma16(zB + ro + c, sZs + wb);
    dma16(bB + ro + c, sBs + wb);
    dma16(dB + ro + c, sDs + wb);
}

// h-blur reading ONLY the wave's own LDS span; boundary taps for lanes 0/63
// come from the Halo registers (no cross-wave LDS -> no barrier needed).
__device__ __forceinline__ void hblur_priv(
    int gy, const float* sZs, const float* sBs, const float* sDs,
    int c, int tl, int wb, const Halo& h, bool eL, bool eR,
    float kd, float ks1, float ks4,
    float4& sb, float4& sd, float4& sz)
{
    if ((unsigned)gy < (unsigned)H_) {   // block-uniform
        const int cL = max(c - 2, wb);        // stay inside own span
        const int cR = min(c + 4, wb + 252);
        float2 lz = *(const float2*)(sZs + cL);
        const float4 cz = *(const float4*)(sZs + c);
        float2 rz = *(const float2*)(sZs + cR);
        float2 lb = *(const float2*)(sBs + cL);
        const float4 cb = *(const float4*)(sBs + c);
        float2 rb = *(const float2*)(sBs + cR);
        float2 ld = *(const float2*)(sDs + cL);
        const float4 cd = *(const float4*)(sDs + c);
        float2 rd = *(const float2*)(sDs + cR);
        if (tl == 0)  { lz = h.lz; lb = h.lb; ld = h.ld; }
        if (tl == 63) { rz = h.rz; rb = h.rb; rd = h.rd; }
        // image-edge taps: poison depth -> w = 0 exactly (matches zero-pad ref)
        if (eL) { lz.x = 1e18f; lz.y = 1e18f; }
        if (eR) { rz.x = 1e18f; rz.y = 1e18f; }
        blur5(lz.x, lz.y, cz.x, cz.y, cz.z,  lb.x, lb.y, cb.x, cb.y, cb.z,
              ld.x, ld.y, cd.x, cd.y, cd.z,  kd, ks1, ks4, sb.x, sd.x);
        blur5(lz.y, cz.x, cz.y, cz.z, cz.w,  lb.y, cb.x, cb.y, cb.z, cb.w,
              ld.y, cd.x, cd.y, cd.z, cd.w,  kd, ks1, ks4, sb.y, sd.y);
        blur5(cz.x, cz.y, cz.z, cz.w, rz.x,  cb.x, cb.y, cb.z, cb.w, rb.x,
              cd.x, cd.y, cd.z, cd.w, rd.x,  kd, ks1, ks4, sb.z, sd.z);
        blur5(cz.y, cz.z, cz.w, rz.x, rz.y,  cb.y, cb.z, cb.w, rb.x, rb.y,
              cd.y, cd.z, cd.w, rd.x, rd.y,  kd, ks1, ks4, sb.w, sd.w);
        sz = cz;
    } else {
        // zero row: vertical tap z=0 -> t=-1 -> w underflows to 0 exact
        sb = make_float4(0.f, 0.f, 0.f, 0.f);
        sd = make_float4(0.f, 0.f, 0.f, 0.f);
        sz = make_float4(0.f, 0.f, 0.f, 0.f);
    }
}

// warmup step I: halo(row I-2), DMA(row I-1 -> slot SD), wait own D_{I}, h-blur.
// Ledger at wait: [D_I(3), A_I(6), D_{I+1}(3)] -> vmcnt(9) retires D_I only.
#define WSTEP(S, SC, SD, I)                                                   \
  {                                                                           \
    Halo h;                                                                   \
    halo_load(y0 + (I) - 2, bB, dB, zB, hl, hr, h);                           \
    FENCE();                                                                  \
    dma_row(y0 + (I) - 1, bB, dB, zB, sZ[SD], sB[SD], sD[SD], c, wb);         \
    FENCE();                                                                  \
    asm volatile("s_waitcnt vmcnt(9)" ::: "memory");                          \
    hblur_priv(y0 + (I) - 2, sZ[SC], sB[SC], sD[SC], c, tl, wb, h, eL, eR,    \
               kd, ks1, ks4, pb[S], pd[S], pz[S]);                            \
  }

// full step I. Issue order (pinned by fences, per-wave FIFO):
//   A_I(6) | D_{I+1}(3) | rb,rd(2) | vmcnt(VN) retires D_I | compute | store
// Steady ledger: [D_I(3), store(1), A_I(6), D_{I+1}(3), rb, rd] -> VN=12.
// I=4 (no prior store): VN=11.  I=11 (no DMA): VN=9.
#define FSTEP(S, S0, S1, S2, S3, S4, SC, SD, I, VN, DODMA)                    \
  {                                                                           \
    Halo h;                                                                   \
    halo_load(y0 + (I) - 2, bB, dB, zB, hl, hr, h);                           \
    FENCE();                                                                  \
    if (DODMA) dma_row(y0 + (I) - 1, bB, dB, zB, sZ[SD], sB[SD], sD[SD], c, wb); \
    FENCE();                                                                  \
    const size_t oo = (size_t)(y0 + (I) - 4) * W_ + c;                        \
    const float4 rb4 = *(const float4*)(bB + oo);                             \
    const float4 rd4 = *(const float4*)(dB + oo);                             \
    FENCE();                                                                  \
    asm volatile("s_waitcnt vmcnt(" #VN ")" ::: "memory");                    \
    hblur_priv(y0 + (I) - 2, sZ[SC], sB[SC], sD[SC], c, tl, wb, h, eL, eR,    \
               kd, ks1, ks4, pb[S], pd[S], pz[S]);                            \
    float4 bm, dm;                                                            \
    blur5(pz[S0].x, pz[S1].x, pz[S2].x, pz[S3].x, pz[S4].x,                   \
          pb[S0].x, pb[S1].x, pb[S2].x, pb[S3].x, pb[S4].x,                   \
          pd[S0].x, pd[S1].x, pd[S2].x, pd[S3].x, pd[S4].x,                   \
          kd, ks1, ks4, bm.x, dm.x);                                          \
    blur5(pz[S0].y, pz[S1].y, pz[S2].y, pz[S3].y, pz[S4].y,                   \
          pb[S0].y, pb[S1].y, pb[S2].y, pb[S3].y, pb[S4].y,                   \
          pd[S0].y, pd[S1].y, pd[S2].y, pd[S3].y, pd[S4].y,                   \
          kd, ks1, ks4, bm.y, dm.y);                                          \
    blur5(pz[S0].z, pz[S1].z, pz[S2].z, pz[S3].z, pz[S4].z,                   \
          pb[S0].z, pb[S1].z, pb[S2].z, pb[S3].z, pb[S4].z,                   \
          pd[S0].z, pd[S1].z, pd[S2].z, pd[S3].z, pd[S4].z,                   \
          kd, ks1, ks4, bm.z, dm.z);                                          \
    blur5(pz[S0].w, pz[S1].w, pz[S2].w, pz[S3].w, pz[S4].w,                   \
          pb[S0].w, pb[S1].w, pb[S2].w, pb[S3].w, pb[S4].w,                   \
          pd[S0].w, pd[S1].w, pd[S2].w, pd[S3].w, pd[S4].w,                   \
          kd, ks1, ks4, bm.w, dm.w);                                          \
    float4 res;                                                               \
    res.x = blend1(rb4.x, rd4.x, bm.x, dm.x, de, dke, ce);                    \
    res.y = blend1(rb4.y, rd4.y, bm.y, dm.y, de, dke, ce);                    \
    res.z = blend1(rb4.z, rd4.z, bm.z, dm.z, de, dke, ce);                    \
    res.w = blend1(rb4.w, rd4.w, bm.w, dm.w, de, dke, ce);                    \
    *(float4*)(outB + oo) = res;                                              \
  }

// Barrier-free wave-private pipeline. Evidence: Rounds 0/2/4/7 all ~52-57us,
// VALUBusy 44-53% across 4 different staging structures -> per-wave stalls
// don't overlap across the SIMD. Round 7's per-step s_barrier convoy-couples
// waves across timeshared SIMDs; here every wave self-paces on its OWN counted
// vmcnt (async DMA into a wave-private LDS span), zero barriers. Cross-wave
// halo (2 cols, lanes 0/63 only) comes from uniform register loads instead.
// LDS: 3 arrays x 2 slots x 4KB = 24KB.
__global__ __launch_bounds__(256, 4)
void bilateral_fused(const float* __restrict__ bright,
                     const float* __restrict__ dark,
                     const float* __restrict__ depths,
                     const float* __restrict__ p_dv,
                     const float* __restrict__ p_sv,
                     const float* __restrict__ p_de,
                     const float* __restrict__ p_deps,
                     const float* __restrict__ p_ce,
                     float* __restrict__ out)
{
    __shared__ __attribute__((aligned(16))) float sZ[2][W_];
    __shared__ __attribute__((aligned(16))) float sB[2][W_];
    __shared__ __attribute__((aligned(16))) float sD[2][W_];

    const float LOG2E = 1.44269504088896340736f;
    const float kd  = -LOG2E / (2.0f * p_dv[0]);   // ~ -1803
    const float ks  = -LOG2E / (2.0f * p_sv[0]);
    const float de  = p_de[0];
    const float dke = p_deps[0];
    const float ce  = p_ce[0];
    const float ks1 = ks;
    const float ks4 = 4.0f * ks;

    const int t  = threadIdx.x;           // 0..255
    const int tl = t & 63;                // lane in wave
    const int c  = 4 * t;                 // cols c..c+3 (= DMA lane offset)
    const int wb = c & ~255;              // wave's 256-float span base
    const int y0 = blockIdx.y * TH;

    const size_t plane = (size_t)H_ * W_;
    const float* bB = bright + (size_t)blockIdx.z * plane;
    const float* dB = dark   + (size_t)blockIdx.z * plane;
    const float* zB = depths + (size_t)blockIdx.z * plane;
    float*     outB = out    + (size_t)blockIdx.z * plane;

    const int  hl = max(wb - 2, 0);        // halo float2 cols [wb-2, wb-1]
    const int  hr = min(wb + 256, W_ - 2); // halo float2 cols [wb+256, wb+257]
    const bool eL = (c == 0);
    const bool eR = (c + 4 >= W_);

    // 5-deep register pipeline of h-blurred rows + center depths
    float4 pb[5], pd[5], pz[5];

    // prologue: DMA first staged row (y0-2) into slot 0
    dma_row(y0 - 2, bB, dB, zB, sZ[0], sB[0], sD[0], c, wb);

    // warmup steps 0..3: rows y0-2 .. y0+1 into pipeline slots 0..3
    // (slot parity: step I consumes slot I&1, stages into (I+1)&1)
    WSTEP(0, 0, 1, 0)
    WSTEP(1, 1, 0, 1)
    WSTEP(2, 0, 1, 2)
    WSTEP(3, 1, 0, 3)

    // steady state steps 4..11: outputs rows y0 .. y0+7
    FSTEP(4, 0, 1, 2, 3, 4,  0, 1,  4, 11, 1)
    FSTEP(0, 1, 2, 3, 4, 0,  1, 0,  5, 12, 1)
    FSTEP(1, 2, 3, 4, 0, 1,  0, 1,  6, 12, 1)
    FSTEP(2, 3, 4, 0, 1, 2,  1, 0,  7, 12, 1)
    FSTEP(3, 4, 0, 1, 2, 3,  0, 1,  8, 12, 1)
    FSTEP(4, 0, 1, 2, 3, 4,  1, 0,  9, 12, 1)
    FSTEP(0, 1, 2, 3, 4, 0,  0, 1, 10, 12, 1)
    FSTEP(1, 2, 3, 4, 0, 1,  1, 0, 11,  9, 0)   // last: no DMA
}

extern "C" void kernel_launch(void* const* d_in, const int* in_sizes, int n_in,
                              void* d_out, int out_size, void* d_ws, size_t ws_size,
                              hipStream_t stream)
{
    const float* bright = (const float*)d_in[0];
    const float* dark   = (const float*)d_in[1];
    const float* depths = (const float*)d_in[2];
    const float* p_dv   = (const float*)d_in[3];
    const float* p_sv   = (const float*)d_in[4];
    const float* p_de   = (const float*)d_in[5];
    const float* p_deps = (const float*)d_in[6];
    const float* p_ce   = (const float*)d_in[7];
    float* out = (float*)d_out;

    const int B = in_sizes[0] / (H_ * W_);

    dim3 grid(1, H_ / TH, B);
    dim3 block(256);
    bilateral_fused<<<grid, block, 0, stream>>>(bright, dark, depths,
                                                p_dv, p_sv, p_de, p_deps, p_ce,
                                                out);
}

// Round 9
// 170.298 us; speedup vs baseline: 1.0719x; 1.0719x over previous
//
#include <hip/hip_runtime.h>

#define TH 8
#define W_ 1024
#define H_ 1024

__device__ __forceinline__ float wexp1(float zp, float iz, float kd, float kspat) {
    const float u = fmaf(zp, iz, -1.0f);
    return __builtin_amdgcn_exp2f(fmaf(u * kd, u, kspat));
}

// 5-tap depth-guided blur of (b,d) around center; taps m2,m1,[c],p1,p2
__device__ __forceinline__ void blur5(
    float zm2, float zm1, float zc, float zp1, float zp2,
    float bm2, float bm1, float bc, float bp1, float bp2,
    float dm2, float dm1, float dc, float dp1, float dp2,
    float kd, float ks1, float ks4,
    float& ob, float& od)
{
    const float iz = __builtin_amdgcn_rcpf(zc);
    const float w0 = wexp1(zm2, iz, kd, ks4);
    const float w1 = wexp1(zm1, iz, kd, ks1);
    const float w3 = wexp1(zp1, iz, kd, ks1);
    const float w4 = wexp1(zp2, iz, kd, ks4);
    const float wr = __builtin_amdgcn_rcpf(1.0f + w0 + w1 + w3 + w4);
    ob = fmaf(w0, bm2, fmaf(w1, bm1, fmaf(w3, bp1, fmaf(w4, bp2, bc)))) * wr;
    od = fmaf(w0, dm2, fmaf(w1, dm1, fmaf(w3, dp1, fmaf(w4, dp2, dc)))) * wr;
}

__device__ __forceinline__ float blend1(float bc, float dc, float bm, float dm,
                                        float de, float dke, float ce) {
    const float devb = __builtin_amdgcn_exp2f(
        de * __builtin_amdgcn_logf(fmaxf(fabsf(bc - bm), 1e-8f))) * ce;
    const float devd = fmaxf(__builtin_amdgcn_exp2f(
        de * __builtin_amdgcn_logf(fmaxf(fabsf(dc - dm), 1e-8f))), dke);
    const float wr = __builtin_amdgcn_rcpf(devb + devd);
    return fmaf(devd, bc, devb * dc) * wr;
}

// horizontal blur of row gy into pipeline slot (sb,sd,sz); 2 px at cols c2,c2+1
__device__ __forceinline__ void stage_row(
    int gy, const float* __restrict__ bB, const float* __restrict__ dB,
    const float* __restrict__ zB,
    int c2, int colL, int colR, bool eL, bool eR,
    float kd, float ks1, float ks4,
    float2& sb, float2& sd, float2& sz)
{
    if ((unsigned)gy < (unsigned)H_) {   // block-uniform
        const size_t ro = (size_t)gy * W_;
        const float2 lb = *(const float2*)(bB + ro + colL);
        const float2 cb = *(const float2*)(bB + ro + c2);
        const float2 rb = *(const float2*)(bB + ro + colR);
        const float2 ld = *(const float2*)(dB + ro + colL);
        const float2 cd = *(const float2*)(dB + ro + c2);
        const float2 rd = *(const float2*)(dB + ro + colR);
        float2 lz = *(const float2*)(zB + ro + colL);
        const float2 cz = *(const float2*)(zB + ro + c2);
        float2 rz = *(const float2*)(zB + ro + colR);
        // image-edge taps: poison depth -> |t| huge -> kd*t^2 = -inf -> w = 0
        // (matches the reference's zero-padding exactly)
        if (eL) { lz.x = 1e18f; lz.y = 1e18f; }
        if (eR) { rz.x = 1e18f; rz.y = 1e18f; }
        // px c2:   taps lz.x lz.y cz.x cz.y rz.x
        // px c2+1: taps lz.y cz.x cz.y rz.x rz.y
        blur5(lz.x, lz.y, cz.x, cz.y, rz.x,  lb.x, lb.y, cb.x, cb.y, rb.x,
              ld.x, ld.y, cd.x, cd.y, rd.x,  kd, ks1, ks4, sb.x, sd.x);
        blur5(lz.y, cz.x, cz.y, rz.x, rz.y,  lb.y, cb.x, cb.y, rb.x, rb.y,
              ld.y, cd.x, cd.y, rd.x, rd.y,  kd, ks1, ks4, sb.y, sd.y);
        sz = cz;
    } else {
        // zero-pad row: z=0 -> vertical tap t=-1 -> w = exp2(kd+ks) = 0 exact
        sb = make_float2(0.f, 0.f);
        sd = make_float2(0.f, 0.f);
        sz = make_float2(0.f, 0.f);
    }
}

// stage row (y0+i-2) into slot S, then vertical blur + blend of row (y0+i-4)
#define STEP(S, S0, S1, S2, S3, S4, I)                                        \
  {                                                                           \
    stage_row(y0 + (I) - 2, bB, dB, zB, c2, colL, colR, eL, eR,               \
              kd, ks1, ks4, pb[S], pd[S], pz[S]);                             \
    float2 bm, dm;                                                            \
    blur5(pz[S0].x, pz[S1].x, pz[S2].x, pz[S3].x, pz[S4].x,                   \
          pb[S0].x, pb[S1].x, pb[S2].x, pb[S3].x, pb[S4].x,                   \
          pd[S0].x, pd[S1].x, pd[S2].x, pd[S3].x, pd[S4].x,                   \
          kd, ks1, ks4, bm.x, dm.x);                                          \
    blur5(pz[S0].y, pz[S1].y, pz[S2].y, pz[S3].y, pz[S4].y,                   \
          pb[S0].y, pb[S1].y, pb[S2].y, pb[S3].y, pb[S4].y,                   \
          pd[S0].y, pd[S1].y, pd[S2].y, pd[S3].y, pd[S4].y,                   \
          kd, ks1, ks4, bm.y, dm.y);                                          \
    const size_t oo = (size_t)(y0 + (I) - 4) * W_ + c2;                       \
    const float2 rb2 = *(const float2*)(bB + oo);                             \
    const float2 rd2 = *(const float2*)(dB + oo);                             \
    float2 res;                                                               \
    res.x = blend1(rb2.x, rd2.x, bm.x, dm.x, de, dke, ce);                    \
    res.y = blend1(rb2.y, rd2.y, bm.y, dm.y, de, dke, ce);                    \
    *(float2*)(outB + oo) = res;                                              \
  }

// Occupancy-via-thread-capacity: Rounds 0-8 data show blocks co-resident at
// 4/CU regardless of grid size (256-thr blocks -> 16 waves/CU, VALUBusy ~46%
// == 16-wave arithmetic exactly). 512-thr blocks x 4/CU = 2048 threads = HW
// thread cap -> 32 waves/CU candidate. 2 cols/thread (float2) halves per-wave
// state: pipeline = 30 VGPR -> total ~60 <= 64, so 8 waves/SIMD HW-allowed.
// No asm/fences/LDS (Rounds 5-8: those spill or convoy; plain Round-0 shape
// is the proven best). launch_bounds(512,4): budget 128, no Round-1 clamp.
__global__ __launch_bounds__(512, 4)
void bilateral_fused(const float* __restrict__ bright,
                     const float* __restrict__ dark,
                     const float* __restrict__ depths,
                     const float* __restrict__ p_dv,
                     const float* __restrict__ p_sv,
                     const float* __restrict__ p_de,
                     const float* __restrict__ p_deps,
                     const float* __restrict__ p_ce,
                     float* __restrict__ out)
{
    const float LOG2E = 1.44269504088896340736f;
    const float kd  = -LOG2E / (2.0f * p_dv[0]);   // ~ -1803
    const float ks  = -LOG2E / (2.0f * p_sv[0]);
    const float de  = p_de[0];
    const float dke = p_deps[0];
    const float ce  = p_ce[0];
    const float ks1 = ks;
    const float ks4 = 4.0f * ks;

    const int t  = threadIdx.x;           // 0..511
    const int c2 = 2 * t;                 // cols c2, c2+1
    const int y0 = blockIdx.y * TH;

    const size_t plane = (size_t)H_ * W_;
    const float* bB = bright + (size_t)blockIdx.z * plane;
    const float* dB = dark   + (size_t)blockIdx.z * plane;
    const float* zB = depths + (size_t)blockIdx.z * plane;
    float*     outB = out    + (size_t)blockIdx.z * plane;

    const int  colL = max(c2 - 2, 0);        // float2 [c2-2,c2-1], 8B aligned
    const int  colR = min(c2 + 2, W_ - 2);   // float2 [c2+2,c2+3]
    const bool eL = (c2 == 0);
    const bool eR = (c2 + 2 >= W_);

    // 5-deep register pipeline: horizontally-blurred (b,d) + center depths
    float2 pb[5], pd[5], pz[5];

    // warm-up: steps i = 0..3 -> slots 0..3 (no output yet)
    stage_row(y0 - 2, bB, dB, zB, c2, colL, colR, eL, eR, kd, ks1, ks4, pb[0], pd[0], pz[0]);
    stage_row(y0 - 1, bB, dB, zB, c2, colL, colR, eL, eR, kd, ks1, ks4, pb[1], pd[1], pz[1]);
    stage_row(y0 + 0, bB, dB, zB, c2, colL, colR, eL, eR, kd, ks1, ks4, pb[2], pd[2], pz[2]);
    stage_row(y0 + 1, bB, dB, zB, c2, colL, colR, eL, eR, kd, ks1, ks4, pb[3], pd[3], pz[3]);

    // steady state: steps i = 4..11, fully static slot rotation (TH = 8)
    STEP(4, 0, 1, 2, 3, 4,  4)
    STEP(0, 1, 2, 3, 4, 0,  5)
    STEP(1, 2, 3, 4, 0, 1,  6)
    STEP(2, 3, 4, 0, 1, 2,  7)
    STEP(3, 4, 0, 1, 2, 3,  8)
    STEP(4, 0, 1, 2, 3, 4,  9)
    STEP(0, 1, 2, 3, 4, 0, 10)
    STEP(1, 2, 3, 4, 0, 1, 11)
}

extern "C" void kernel_launch(void* const* d_in, const int* in_sizes, int n_in,
                              void* d_out, int out_size, void* d_ws, size_t ws_size,
                              hipStream_t stream)
{
    const float* bright = (const float*)d_in[0];
    const float* dark   = (const float*)d_in[1];
    const float* depths = (const float*)d_in[2];
    const float* p_dv   = (const float*)d_in[3];
    const float* p_sv   = (const float*)d_in[4];
    const float* p_de   = (const float*)d_in[5];
    const float* p_deps = (const float*)d_in[6];
    const float* p_ce   = (const float*)d_in[7];
    float* out = (float*)d_out;

    const int B = in_sizes[0] / (H_ * W_);

    dim3 grid(1, H_ / TH, B);
    dim3 block(512);
    bilateral_fused<<<grid, block, 0, stream>>>(bright, dark, depths,
                                                p_dv, p_sv, p_de, p_deps, p_ce,
                                                out);
}

// Round 10
// 157.515 us; speedup vs baseline: 1.1589x; 1.0812x over previous
//
#include <hip/hip_runtime.h>

#define TH 8
#define W_ 1024
#define H_ 1024

__device__ __forceinline__ float wexp1(float zp, float iz, float kd, float kspat) {
    const float u = fmaf(zp, iz, -1.0f);
    return __builtin_amdgcn_exp2f(fmaf(u * kd, u, kspat));
}

// 5-tap depth-guided blur of (b,d) around center; taps m2,m1,[c],p1,p2
__device__ __forceinline__ void blur5(
    float zm2, float zm1, float zc, float zp1, float zp2,
    float bm2, float bm1, float bc, float bp1, float bp2,
    float dm2, float dm1, float dc, float dp1, float dp2,
    float kd, float ks1, float ks4,
    float& ob, float& od)
{
    const float iz = __builtin_amdgcn_rcpf(zc);
    const float w0 = wexp1(zm2, iz, kd, ks4);
    const float w1 = wexp1(zm1, iz, kd, ks1);
    const float w3 = wexp1(zp1, iz, kd, ks1);
    const float w4 = wexp1(zp2, iz, kd, ks4);
    const float wr = __builtin_amdgcn_rcpf(1.0f + w0 + w1 + w3 + w4);
    ob = fmaf(w0, bm2, fmaf(w1, bm1, fmaf(w3, bp1, fmaf(w4, bp2, bc)))) * wr;
    od = fmaf(w0, dm2, fmaf(w1, dm1, fmaf(w3, dp1, fmaf(w4, dp2, dc)))) * wr;
}

__device__ __forceinline__ float blend1(float bc, float dc, float bm, float dm,
                                        float de, float dke, float ce) {
    const float devb = __builtin_amdgcn_exp2f(
        de * __builtin_amdgcn_logf(fmaxf(fabsf(bc - bm), 1e-8f))) * ce;
    const float devd = fmaxf(__builtin_amdgcn_exp2f(
        de * __builtin_amdgcn_logf(fmaxf(fabsf(dc - dm), 1e-8f))), dke);
    const float wr = __builtin_amdgcn_rcpf(devb + devd);
    return fmaf(devd, bc, devb * dc) * wr;
}

// horizontal blur of row gy into pipeline slot (sb,sd,sz); 4 px at cols c..c+3
__device__ __forceinline__ void stage_row(
    int gy, const float* __restrict__ bB, const float* __restrict__ dB,
    const float* __restrict__ zB,
    int c, int colL2, int colR2, bool eL, bool eR,
    float kd, float ks1, float ks4,
    float4& sb, float4& sd, float4& sz)
{
    if ((unsigned)gy < (unsigned)H_) {   // block-uniform
        const size_t ro = (size_t)gy * W_;
        const float2 lb = *(const float2*)(bB + ro + colL2);
        const float4 cb = *(const float4*)(bB + ro + c);
        const float2 rb = *(const float2*)(bB + ro + colR2);
        const float2 ld = *(const float2*)(dB + ro + colL2);
        const float4 cd = *(const float4*)(dB + ro + c);
        const float2 rd = *(const float2*)(dB + ro + colR2);
        float2 lz = *(const float2*)(zB + ro + colL2);
        const float4 cz = *(const float4*)(zB + ro + c);
        float2 rz = *(const float2*)(zB + ro + colR2);
        // image-edge taps: poison depth -> |t| huge -> kd*t^2 = -inf -> w = 0
        // (matches the reference's zero-padding exactly)
        if (eL) { lz.x = 1e18f; lz.y = 1e18f; }
        if (eR) { rz.x = 1e18f; rz.y = 1e18f; }
        // window cols: lz(c-2,c-1) cz(c..c+3) rz(c+4,c+5)
        blur5(lz.x, lz.y, cz.x, cz.y, cz.z,  lb.x, lb.y, cb.x, cb.y, cb.z,
              ld.x, ld.y, cd.x, cd.y, cd.z,  kd, ks1, ks4, sb.x, sd.x);
        blur5(lz.y, cz.x, cz.y, cz.z, cz.w,  lb.y, cb.x, cb.y, cb.z, cb.w,
              ld.y, cd.x, cd.y, cd.z, cd.w,  kd, ks1, ks4, sb.y, sd.y);
        blur5(cz.x, cz.y, cz.z, cz.w, rz.x,  cb.x, cb.y, cb.z, cb.w, rb.x,
              cd.x, cd.y, cd.z, cd.w, rd.x,  kd, ks1, ks4, sb.z, sd.z);
        blur5(cz.y, cz.z, cz.w, rz.x, rz.y,  cb.y, cb.z, cb.w, rb.x, rb.y,
              cd.y, cd.z, cd.w, rd.x, rd.y,  kd, ks1, ks4, sb.w, sd.w);
        sz = cz;
    } else {
        // zero-pad row: z=0 -> vertical tap t=-1 -> w = exp2(kd+ks) = 0 exact
        sb = make_float4(0.f, 0.f, 0.f, 0.f);
        sd = make_float4(0.f, 0.f, 0.f, 0.f);
        sz = make_float4(0.f, 0.f, 0.f, 0.f);
    }
}

// stage row (y0+i-2) into slot S, then vertical blur + blend of row (y0+i-4)
#define STEP(S, S0, S1, S2, S3, S4, I)                                        \
  {                                                                           \
    stage_row(y0 + (I) - 2, bB, dB, zB, c, colL2, colR2, eL, eR,              \
              kd, ks1, ks4, pb[S], pd[S], pz[S]);                             \
    float4 bm, dm;                                                            \
    blur5(pz[S0].x, pz[S1].x, pz[S2].x, pz[S3].x, pz[S4].x,                   \
          pb[S0].x, pb[S1].x, pb[S2].x, pb[S3].x, pb[S4].x,                   \
          pd[S0].x, pd[S1].x, pd[S2].x, pd[S3].x, pd[S4].x,                   \
          kd, ks1, ks4, bm.x, dm.x);                                          \
    blur5(pz[S0].y, pz[S1].y, pz[S2].y, pz[S3].y, pz[S4].y,                   \
          pb[S0].y, pb[S1].y, pb[S2].y, pb[S3].y, pb[S4].y,                   \
          pd[S0].y, pd[S1].y, pd[S2].y, pd[S3].y, pd[S4].y,                   \
          kd, ks1, ks4, bm.y, dm.y);                                          \
    blur5(pz[S0].z, pz[S1].z, pz[S2].z, pz[S3].z, pz[S4].z,                   \
          pb[S0].z, pb[S1].z, pb[S2].z, pb[S3].z, pb[S4].z,                   \
          pd[S0].z, pd[S1].z, pd[S2].z, pd[S3].z, pd[S4].z,                   \
          kd, ks1, ks4, bm.z, dm.z);                                          \
    blur5(pz[S0].w, pz[S1].w, pz[S2].w, pz[S3].w, pz[S4].w,                   \
          pb[S0].w, pb[S1].w, pb[S2].w, pb[S3].w, pb[S4].w,                   \
          pd[S0].w, pd[S1].w, pd[S2].w, pd[S3].w, pd[S4].w,                   \
          kd, ks1, ks4, bm.w, dm.w);                                          \
    const size_t oo = (size_t)(y0 + (I) - 4) * W_ + c;                        \
    const float4 rb4 = *(const float4*)(bB + oo);                             \
    const float4 rd4 = *(const float4*)(dB + oo);                             \
    float4 res;                                                               \
    res.x = blend1(rb4.x, rd4.x, bm.x, dm.x, de, dke, ce);                    \
    res.y = blend1(rb4.y, rd4.y, bm.y, dm.y, de, dke, ce);                    \
    res.z = blend1(rb4.z, rd4.z, bm.z, dm.z, de, dke, ce);                    \
    res.w = blend1(rb4.w, rd4.w, bm.w, dm.w, de, dke, ce);                    \
    *(float4*)(outB + oo) = res;                                              \
  }

// Round-0 proven shape (52us best, VGPR 60, no spills) + ONE change:
// XCD-contiguous y-swizzle. Grid (1,128,8): linear id = y + 128z, 128%8==0
// -> XCD = y%8, so vertically ADJACENT row-tiles (sharing 4 halo rows = 33%
// of row reads) always land on DIFFERENT XCD L2s. Swizzle yt=((y&7)<<4)|(y>>3)
// (bijective: 128 = 8x16) gives each XCD a contiguous 128-row band per image:
// halo rows become XCD-local L2 hits instead of duplicate L3/HBM fetches.
__global__ __launch_bounds__(256, 4)
void bilateral_fused(const float* __restrict__ bright,
                     const float* __restrict__ dark,
                     const float* __restrict__ depths,
                     const float* __restrict__ p_dv,
                     const float* __restrict__ p_sv,
                     const float* __restrict__ p_de,
                     const float* __restrict__ p_deps,
                     const float* __restrict__ p_ce,
                     float* __restrict__ out)
{
    const float LOG2E = 1.44269504088896340736f;
    const float kd  = -LOG2E / (2.0f * p_dv[0]);   // ~ -1803
    const float ks  = -LOG2E / (2.0f * p_sv[0]);
    const float de  = p_de[0];
    const float dke = p_deps[0];
    const float ce  = p_ce[0];
    const float ks1 = ks;
    const float ks4 = 4.0f * ks;

    const int t  = threadIdx.x;           // 0..255
    const int c  = 4 * t;                 // cols c..c+3

    // XCD-aware swizzle: dispatch-order XCD = blockIdx.y & 7; map each XCD to
    // a contiguous band of 16 row-tiles. Bijection on [0,128).
    const int yl = blockIdx.y;
    const int yt = ((yl & 7) << 4) | (yl >> 3);
    const int y0 = yt * TH;

    const size_t plane = (size_t)H_ * W_;
    const float* bB = bright + (size_t)blockIdx.z * plane;
    const float* dB = dark   + (size_t)blockIdx.z * plane;
    const float* zB = depths + (size_t)blockIdx.z * plane;
    float*     outB = out    + (size_t)blockIdx.z * plane;

    const int  colL2 = max(c - 2, 0);        // float2 [c-2,c-1], 8B aligned
    const int  colR2 = min(c + 4, W_ - 2);   // float2 [c+4,c+5]
    const bool eL = (c == 0);
    const bool eR = (c + 4 >= W_);

    // 5-deep register pipeline: horizontally-blurred (b,d) + center depths
    float4 pb[5], pd[5], pz[5];

    // warm-up: steps i = 0..3 -> slots 0..3 (no output yet)
    stage_row(y0 - 2, bB, dB, zB, c, colL2, colR2, eL, eR, kd, ks1, ks4, pb[0], pd[0], pz[0]);
    stage_row(y0 - 1, bB, dB, zB, c, colL2, colR2, eL, eR, kd, ks1, ks4, pb[1], pd[1], pz[1]);
    stage_row(y0 + 0, bB, dB, zB, c, colL2, colR2, eL, eR, kd, ks1, ks4, pb[2], pd[2], pz[2]);
    stage_row(y0 + 1, bB, dB, zB, c, colL2, colR2, eL, eR, kd, ks1, ks4, pb[3], pd[3], pz[3]);

    // steady state: steps i = 4..11, fully static slot rotation (TH = 8)
    STEP(4, 0, 1, 2, 3, 4,  4)
    STEP(0, 1, 2, 3, 4, 0,  5)
    STEP(1, 2, 3, 4, 0, 1,  6)
    STEP(2, 3, 4, 0, 1, 2,  7)
    STEP(3, 4, 0, 1, 2, 3,  8)
    STEP(4, 0, 1, 2, 3, 4,  9)
    STEP(0, 1, 2, 3, 4, 0, 10)
    STEP(1, 2, 3, 4, 0, 1, 11)
}

extern "C" void kernel_launch(void* const* d_in, const int* in_sizes, int n_in,
                              void* d_out, int out_size, void* d_ws, size_t ws_size,
                              hipStream_t stream)
{
    const float* bright = (const float*)d_in[0];
    const float* dark   = (const float*)d_in[1];
    const float* depths = (const float*)d_in[2];
    const float* p_dv   = (const float*)d_in[3];
    const float* p_sv   = (const float*)d_in[4];
    const float* p_de   = (const float*)d_in[5];
    const float* p_deps = (const float*)d_in[6];
    const float* p_ce   = (const float*)d_in[7];
    float* out = (float*)d_out;

    const int B = in_sizes[0] / (H_ * W_);

    dim3 grid(1, H_ / TH, B);
    dim3 block(256);
    bilateral_fused<<<grid, block, 0, stream>>>(bright, dark, depths,
                                                p_dv, p_sv, p_de, p_deps, p_ce,
                                                out);
}

// Round 11
// 156.664 us; speedup vs baseline: 1.1652x; 1.0054x over previous
//
#include <hip/hip_runtime.h>

#define TH 8
#define W_ 1024
#define H_ 1024

__device__ __forceinline__ float wexp1(float zp, float iz, float kd, float kspat) {
    const float u = fmaf(zp, iz, -1.0f);
    return __builtin_amdgcn_exp2f(fmaf(u * kd, u, kspat));
}

// 5-tap depth-guided blur of (b,d) around center; taps m2,m1,[c],p1,p2
__device__ __forceinline__ void blur5(
    float zm2, float zm1, float zc, float zp1, float zp2,
    float bm2, float bm1, float bc, float bp1, float bp2,
    float dm2, float dm1, float dc, float dp1, float dp2,
    float kd, float ks1, float ks4,
    float& ob, float& od)
{
    const float iz = __builtin_amdgcn_rcpf(zc);
    const float w0 = wexp1(zm2, iz, kd, ks4);
    const float w1 = wexp1(zm1, iz, kd, ks1);
    const float w3 = wexp1(zp1, iz, kd, ks1);
    const float w4 = wexp1(zp2, iz, kd, ks4);
    const float wr = __builtin_amdgcn_rcpf(1.0f + w0 + w1 + w3 + w4);
    ob = fmaf(w0, bm2, fmaf(w1, bm1, fmaf(w3, bp1, fmaf(w4, bp2, bc)))) * wr;
    od = fmaf(w0, dm2, fmaf(w1, dm1, fmaf(w3, dp1, fmaf(w4, dp2, dc)))) * wr;
}

__device__ __forceinline__ float blend1(float bc, float dc, float bm, float dm,
                                        float de, float dke, float ce) {
    const float devb = __builtin_amdgcn_exp2f(
        de * __builtin_amdgcn_logf(fmaxf(fabsf(bc - bm), 1e-8f))) * ce;
    const float devd = fmaxf(__builtin_amdgcn_exp2f(
        de * __builtin_amdgcn_logf(fmaxf(fabsf(dc - dm), 1e-8f))), dke);
    const float wr = __builtin_amdgcn_rcpf(devb + devd);
    return fmaf(devd, bc, devb * dc) * wr;
}

// horizontal blur of row gy into (sb,sd,sz); 4 px at cols c..c+3
__device__ __forceinline__ void stage_row(
    int gy, const float* __restrict__ bB, const float* __restrict__ dB,
    const float* __restrict__ zB,
    int c, int colL2, int colR2, bool eL, bool eR,
    float kd, float ks1, float ks4,
    float4& sb, float4& sd, float4& sz)
{
    if ((unsigned)gy < (unsigned)H_) {   // block-uniform
        const size_t ro = (size_t)gy * W_;
        const float2 lb = *(const float2*)(bB + ro + colL2);
        const float4 cb = *(const float4*)(bB + ro + c);
        const float2 rb = *(const float2*)(bB + ro + colR2);
        const float2 ld = *(const float2*)(dB + ro + colL2);
        const float4 cd = *(const float4*)(dB + ro + c);
        const float2 rd = *(const float2*)(dB + ro + colR2);
        float2 lz = *(const float2*)(zB + ro + colL2);
        const float4 cz = *(const float4*)(zB + ro + c);
        float2 rz = *(const float2*)(zB + ro + colR2);
        // image-edge taps: poison depth -> |t| huge -> kd*t^2 = -inf -> w = 0
        // (matches the reference's zero-padding exactly)
        if (eL) { lz.x = 1e18f; lz.y = 1e18f; }
        if (eR) { rz.x = 1e18f; rz.y = 1e18f; }
        // window cols: lz(c-2,c-1) cz(c..c+3) rz(c+4,c+5)
        blur5(lz.x, lz.y, cz.x, cz.y, cz.z,  lb.x, lb.y, cb.x, cb.y, cb.z,
              ld.x, ld.y, cd.x, cd.y, cd.z,  kd, ks1, ks4, sb.x, sd.x);
        blur5(lz.y, cz.x, cz.y, cz.z, cz.w,  lb.y, cb.x, cb.y, cb.z, cb.w,
              ld.y, cd.x, cd.y, cd.z, cd.w,  kd, ks1, ks4, sb.y, sd.y);
        blur5(cz.x, cz.y, cz.z, cz.w, rz.x,  cb.x, cb.y, cb.z, cb.w, rb.x,
              cd.x, cd.y, cd.z, cd.w, rd.x,  kd, ks1, ks4, sb.z, sd.z);
        blur5(cz.y, cz.z, cz.w, rz.x, rz.y,  cb.y, cb.z, cb.w, rb.x, rb.y,
              cd.y, cd.z, cd.w, rd.x, rd.y,  kd, ks1, ks4, sb.w, sd.w);
        sz = cz;
    } else {
        // zero-pad row: z=0 -> vertical tap t=-1 -> w = exp2(kd+ks) = 0 exact
        sb = make_float4(0.f, 0.f, 0.f, 0.f);
        sd = make_float4(0.f, 0.f, 0.f, 0.f);
        sz = make_float4(0.f, 0.f, 0.f, 0.f);
    }
}

// I-cache experiment (Round 11): the 12 fully-unrolled steps were ~40KB of
// straight-line code, exceeding the 32KB L1I; 4 blocks/CU at drifting phases
// thrash it. I-fetch stall is invisible in every counter collected so far —
// matching the unattributed ~5.6K cy/step stall (wall 10.4K, issue 4.8K,
// data-memory floors ~2-3K). Loop-ified body: ~3.3KB hot loop, fits L1I.
// Named slots + explicit rotation keep all indexing static (no scratch).
// Everything else identical to Round 10 (swizzle kept: FETCH 99->96.6 MB).
__global__ __launch_bounds__(256, 4)
void bilateral_fused(const float* __restrict__ bright,
                     const float* __restrict__ dark,
                     const float* __restrict__ depths,
                     const float* __restrict__ p_dv,
                     const float* __restrict__ p_sv,
                     const float* __restrict__ p_de,
                     const float* __restrict__ p_deps,
                     const float* __restrict__ p_ce,
                     float* __restrict__ out)
{
    const float LOG2E = 1.44269504088896340736f;
    const float kd  = -LOG2E / (2.0f * p_dv[0]);   // ~ -1803
    const float ks  = -LOG2E / (2.0f * p_sv[0]);
    const float de  = p_de[0];
    const float dke = p_deps[0];
    const float ce  = p_ce[0];
    const float ks1 = ks;
    const float ks4 = 4.0f * ks;

    const int t  = threadIdx.x;           // 0..255
    const int c  = 4 * t;                 // cols c..c+3

    // XCD-aware swizzle (Round 10): contiguous 16-tile band per XCD
    const int yl = blockIdx.y;
    const int yt = ((yl & 7) << 4) | (yl >> 3);
    const int y0 = yt * TH;

    const size_t plane = (size_t)H_ * W_;
    const float* bB = bright + (size_t)blockIdx.z * plane;
    const float* dB = dark   + (size_t)blockIdx.z * plane;
    const float* zB = depths + (size_t)blockIdx.z * plane;
    float*     outB = out    + (size_t)blockIdx.z * plane;

    const int  colL2 = max(c - 2, 0);        // float2 [c-2,c-1], 8B aligned
    const int  colR2 = min(c + 4, W_ - 2);   // float2 [c+4,c+5]
    const bool eL = (c == 0);
    const bool eR = (c + 4 >= W_);

    // 5-deep register pipeline, NAMED slots (static indexing, no scratch)
    float4 pb0, pb1, pb2, pb3, pb4;
    float4 pd0, pd1, pd2, pd3, pd4;
    float4 pz0, pz1, pz2, pz3, pz4;
    pb0 = pb1 = pb2 = pb3 = make_float4(0.f, 0.f, 0.f, 0.f);
    pd0 = pd1 = pd2 = pd3 = make_float4(0.f, 0.f, 0.f, 0.f);
    pz0 = pz1 = pz2 = pz3 = make_float4(0.f, 0.f, 0.f, 0.f);

    // warm-up: stage rows y0-2 .. y0+1, shifting into slots 0..3
    #pragma unroll 1
    for (int i = 0; i < 4; ++i) {
        float4 nb, nd, nz;
        stage_row(y0 + i - 2, bB, dB, zB, c, colL2, colR2, eL, eR,
                  kd, ks1, ks4, nb, nd, nz);
        pb0 = pb1; pb1 = pb2; pb2 = pb3; pb3 = nb;
        pd0 = pd1; pd1 = pd2; pd2 = pd3; pd3 = nd;
        pz0 = pz1; pz1 = pz2; pz2 = pz3; pz3 = nz;
    }

    // steady state: 8 iterations, output rows y0 .. y0+7
    #pragma unroll 1
    for (int i = 4; i < 12; ++i) {
        stage_row(y0 + i - 2, bB, dB, zB, c, colL2, colR2, eL, eR,
                  kd, ks1, ks4, pb4, pd4, pz4);
        float4 bm, dm;
        blur5(pz0.x, pz1.x, pz2.x, pz3.x, pz4.x,
              pb0.x, pb1.x, pb2.x, pb3.x, pb4.x,
              pd0.x, pd1.x, pd2.x, pd3.x, pd4.x,
              kd, ks1, ks4, bm.x, dm.x);
        blur5(pz0.y, pz1.y, pz2.y, pz3.y, pz4.y,
              pb0.y, pb1.y, pb2.y, pb3.y, pb4.y,
              pd0.y, pd1.y, pd2.y, pd3.y, pd4.y,
              kd, ks1, ks4, bm.y, dm.y);
        blur5(pz0.z, pz1.z, pz2.z, pz3.z, pz4.z,
              pb0.z, pb1.z, pb2.z, pb3.z, pb4.z,
              pd0.z, pd1.z, pd2.z, pd3.z, pd4.z,
              kd, ks1, ks4, bm.z, dm.z);
        blur5(pz0.w, pz1.w, pz2.w, pz3.w, pz4.w,
              pb0.w, pb1.w, pb2.w, pb3.w, pb4.w,
              pd0.w, pd1.w, pd2.w, pd3.w, pd4.w,
              kd, ks1, ks4, bm.w, dm.w);
        const size_t oo = (size_t)(y0 + i - 4) * W_ + c;
        const float4 rb4 = *(const float4*)(bB + oo);
        const float4 rd4 = *(const float4*)(dB + oo);
        float4 res;
        res.x = blend1(rb4.x, rd4.x, bm.x, dm.x, de, dke, ce);
        res.y = blend1(rb4.y, rd4.y, bm.y, dm.y, de, dke, ce);
        res.z = blend1(rb4.z, rd4.z, bm.z, dm.z, de, dke, ce);
        res.w = blend1(rb4.w, rd4.w, bm.w, dm.w, de, dke, ce);
        *(float4*)(outB + oo) = res;
        // rotate pipeline (static moves; compiler pairs into b64 copies)
        pb0 = pb1; pb1 = pb2; pb2 = pb3; pb3 = pb4;
        pd0 = pd1; pd1 = pd2; pd2 = pd3; pd3 = pd4;
        pz0 = pz1; pz1 = pz2; pz2 = pz3; pz3 = pz4;
    }
}

extern "C" void kernel_launch(void* const* d_in, const int* in_sizes, int n_in,
                              void* d_out, int out_size, void* d_ws, size_t ws_size,
                              hipStream_t stream)
{
    const float* bright = (const float*)d_in[0];
    const float* dark   = (const float*)d_in[1];
    const float* depths = (const float*)d_in[2];
    const float* p_dv   = (const float*)d_in[3];
    const float* p_sv   = (const float*)d_in[4];
    const float* p_de   = (const float*)d_in[5];
    const float* p_deps = (const float*)d_in[6];
    const float* p_ce   = (const float*)d_in[7];
    float* out = (float*)d_out;

    const int B = in_sizes[0] / (H_ * W_);

    dim3 grid(1, H_ / TH, B);
    dim3 block(256);
    bilateral_fused<<<grid, block, 0, stream>>>(bright, dark, depths,
                                                p_dv, p_sv, p_de, p_deps, p_ce,
                                                out);
}